// Round 4
// baseline (596.090 us; speedup 1.0000x reference)
//
#include <hip/hip_runtime.h>
#include <cstdint>
#include <cstddef>

// MoE layer, MI355X. Round 7 (resubmit — round 3 hit a GPU-broker timeout,
// no measurement): transpose_cvt kernels ELIMINATED — GEMM stages B directly
// from f32 [K][N] weights (k-strided wave-coalesced dword loads, RNE __bf16
// cvt, XOR-swizzled ds_write_b128 into the unchanged ldsB layout).
// Saves ~400MB of relayout HBM traffic + 2 launches. init folded into
// count_offsets (7 launches total). Single-buffer 32KB LDS (5 blocks/CU),
// XCD swizzle, split-K x2 GEMM2 kept from round 6.
// T=4096, D=1024, F=4096, E=8, top-2. Padded slots: 9216.

#define D_MODEL 1024
#define D_FF    4096
#define NEXP    8
#define TOKENS  4096
#define SLOTS   8192
#define SLOTSP  9216

typedef __bf16 bf16x8 __attribute__((ext_vector_type(8)));
typedef float  f32x4  __attribute__((ext_vector_type(4)));

static __device__ __forceinline__ unsigned short f2bf(float f) {
  unsigned int u = __float_as_uint(f);
  u += 0x7fffu + ((u >> 16) & 1u);   // RNE
  return (unsigned short)(u >> 16);
}

static __device__ __forceinline__ void async_ld16(const void* g, void* l) {
  __builtin_amdgcn_global_load_lds(
      (const __attribute__((address_space(1))) void*)g,
      (__attribute__((address_space(3))) void*)l, 16, 0, 0);
}

// ---------------- setup kernels ----------------

// one wave per token; no atomics
__global__ __launch_bounds__(256) void router_kernel(
    const float* __restrict__ x, const float* __restrict__ gw,
    float* __restrict__ out_logits, float* __restrict__ out_idx,
    float* __restrict__ out_w)
{
  const int w = threadIdx.x >> 6, lane = threadIdx.x & 63;
  const int t = blockIdx.x * 4 + w;
  float p[NEXP];
#pragma unroll
  for (int e = 0; e < NEXP; ++e) p[e] = 0.f;
  const float* xr = x + (size_t)t * D_MODEL;
#pragma unroll 4
  for (int i = 0; i < D_MODEL / 64; ++i) {
    const int d = i * 64 + lane;
    const float xv = xr[d];
    const float* g = gw + (size_t)d * NEXP;
#pragma unroll
    for (int e = 0; e < NEXP; ++e) p[e] += xv * g[e];
  }
#pragma unroll
  for (int e = 0; e < NEXP; ++e) {
#pragma unroll
    for (int s = 1; s < 64; s <<= 1) p[e] += __shfl_xor(p[e], s, 64);
  }
  if (lane == 0) {
    int i0 = 0;
#pragma unroll
    for (int e = 1; e < NEXP; ++e) if (p[e] > p[i0]) i0 = e;
    int i1 = (i0 == 0) ? 1 : 0;
#pragma unroll
    for (int e = 0; e < NEXP; ++e)
      if (e != i0 && p[e] > p[i1]) i1 = e;
    const float w0 = 1.f / (1.f + __expf(p[i1] - p[i0]));
#pragma unroll
    for (int e = 0; e < NEXP; ++e) out_logits[(size_t)t * NEXP + e] = p[e];
    out_idx[t * 2 + 0] = (float)i0;
    out_idx[t * 2 + 1] = (float)i1;
    out_w[t * 2 + 0] = w0;
    out_w[t * 2 + 1] = 1.f - w0;
  }
}

// single block: tok_list init + histogram + padded offsets + block map + cursors
// wsI: [8..16)=cursor [16..25)=po [25]=nb [32..104)=blk_e [128..200)=blk_gr0
__global__ __launch_bounds__(256) void count_offsets_kernel(
    const float* __restrict__ out_idx, int* __restrict__ wsI,
    int* __restrict__ tok_list)
{
  __shared__ int hist[NEXP];
  const int tid = threadIdx.x;
  // fold former init_kernel: pad-slot sentinel
  for (int i = tid; i < SLOTSP; i += 256) tok_list[i] = -1;
  if (tid < NEXP) hist[tid] = 0;
  if (tid < NEXP) wsI[8 + tid] = 0;   // cursors
  __syncthreads();
  int c[NEXP];
#pragma unroll
  for (int e = 0; e < NEXP; ++e) c[e] = 0;
  for (int p = tid; p < SLOTS; p += 256) c[(int)out_idx[p]]++;  // coalesced
#pragma unroll
  for (int e = 0; e < NEXP; ++e) if (c[e]) atomicAdd(&hist[e], c[e]);
  __syncthreads();
  if (tid == 0) {
    int s = 0, nb = 0;
    for (int e = 0; e < NEXP; ++e) {
      wsI[16 + e] = s;
      const int nblk = (hist[e] + 127) >> 7;
      for (int j = 0; j < nblk; ++j) {
        wsI[32 + nb] = e;
        wsI[128 + nb] = s + j * 128;
        ++nb;
      }
      s += nblk << 7;
    }
    wsI[16 + NEXP] = s;
    wsI[25] = nb;
  }
}

// ballot-aggregated per-wave atomics (~8 per wave instead of 64)
__global__ void scatter_kernel(const float* __restrict__ out_idx,
                               int* __restrict__ cursor,
                               const int* __restrict__ po,
                               int* __restrict__ pair_slot,
                               int* __restrict__ tok_list)
{
  const int p = blockIdx.x * 256 + threadIdx.x;
  const int lane = threadIdx.x & 63;
  const int e = (int)out_idx[p];
  int pos = 0;
#pragma unroll
  for (int e8 = 0; e8 < NEXP; ++e8) {
    const unsigned long long m = __ballot(e == e8);
    if (m) {
      const int leader = __ffsll((long long)m) - 1;
      int base = 0;
      if (lane == leader) base = atomicAdd(&cursor[e8], (int)__popcll(m));
      base = __shfl(base, leader, 64);
      if (e == e8)
        pos = po[e8] + base +
              (int)__popcll(m & ((1ull << lane) - 1ull));
    }
  }
  tok_list[pos] = p >> 1;
  pair_slot[p] = pos;
}

// gather x rows into slot order, f32 -> bf16
__global__ __launch_bounds__(256) void gather_cvt(
    const float* __restrict__ x, const int* __restrict__ tok_list,
    unsigned short* __restrict__ xg)
{
  const int gid = blockIdx.x * 256 + threadIdx.x;
  const int row = gid >> 7, seg = gid & 127;
  const int tok = tok_list[row];
  if (tok < 0) return;
  const float* src = x + (size_t)tok * D_MODEL + seg * 8;
  const float4 a = *(const float4*)(src);
  const float4 b = *(const float4*)(src + 4);
  ushort4 lo = make_ushort4(f2bf(a.x), f2bf(a.y), f2bf(a.z), f2bf(a.w));
  ushort4 hi = make_ushort4(f2bf(b.x), f2bf(b.y), f2bf(b.z), f2bf(b.w));
  unsigned short* d = xg + (size_t)row * D_MODEL + seg * 8;
  *(ushort4*)(d) = lo;
  *(ushort4*)(d + 4) = hi;
}

// ------- MFMA grouped GEMM, BK=64, single-buffer, split-K, fused B-cvt -------
// ldsA: 128 rows x 8 segs(16B); data seg s of row r at slot s^(r&7); staged via
//   global_load_lds with pre-swizzled per-lane global source (unchanged).
// ldsB: same layout, but staged directly from f32 [K][N] weights: thread
//   (wave wv, lane nloc) handles columns n=nloc+64*jn, k-octets o=wv+4*jo;
//   8 k-strided dword loads (wave-coalesced 256B: n contiguous across lanes),
//   RNE __bf16 cvt, one ds_write_b128 at slot o^(n&7)  -> identical bytes to
//   the old transpose_cvt + global_load_lds path, so fragment reads unchanged.
// Fragment read: seg = ks2*4+q -> slot = (q ^ (m15&7)) ^ (ks2*4).
// 32KB LDS -> 5 blocks/CU co-resident. Split-K via blockIdx.z (partials f32,
// bias added by split 0 only; RELU instance never split).
template <int RELU>
__global__ __launch_bounds__(256) void gemm_mfma(
    const unsigned short* __restrict__ A, const float* __restrict__ W,
    const float* __restrict__ bias, void* __restrict__ Cout,
    const int* __restrict__ wsI, int K, int N)
{
  // bijective XCD-aware swizzle within each z-slice (nwg/slice % 8 == 0:
  // 2304 for GEMM1, 576 for GEMM2).
  const int gx = gridDim.x;
  const int nwg = gx * gridDim.y;
  const int cpx = nwg >> 3;
  int f = blockIdx.y * gx + blockIdx.x;
  f = (f & 7) * cpx + (f >> 3);
  const int bx = f % gx;
  const int by = f / gx;

  if (by >= wsI[25]) return;
  const int e   = wsI[32 + by];
  const int gr0 = wsI[128 + by];
  const int col0 = bx * 128;

  const int klen = K / gridDim.z;
  const int kbeg = blockIdx.z * klen;
  const int kend = kbeg + klen;

  __shared__ unsigned short ldsA[128 * 64];
  __shared__ unsigned short ldsB[128 * 64];

  const int tid = threadIdx.x;
  const int lane = tid & 63;
  const int w = tid >> 6;
  const int wr = w >> 1, wc = w & 1;
  const int m15 = lane & 15, q = lane >> 4;

  f32x4 zero = {0.f, 0.f, 0.f, 0.f};
  f32x4 acc[4][4];
#pragma unroll
  for (int mt = 0; mt < 4; ++mt)
#pragma unroll
    for (int nt = 0; nt < 4; ++nt) acc[mt][nt] = zero;

  // A staging offsets (halfs): row0 = tid>>3, sg = (tid&7)^((tid>>3)&7)
  const size_t off0 = (size_t)(tid >> 3) * K + ((tid & 7) ^ ((tid >> 3) & 7)) * 8;
  const size_t jstep = (size_t)32 * K;
  const unsigned short* Abase = A + (size_t)gr0 * K;

  // B staging: column base for this thread (f32 weights, row stride N)
  const int nloc = tid & 63;
  const int wv = tid >> 6;
  const float* Wc0 = W + (size_t)e * K * N + (col0 + nloc);

  const int sw = q ^ (m15 & 7);   // fragment slot base

  for (int kk = kbeg; kk < kend; kk += 64) {
    // A: async global->LDS (bf16 source)
#pragma unroll
    for (int j = 0; j < 4; ++j)
      async_ld16(Abase + off0 + j * jstep + kk, &ldsA[(j * 256 + tid) * 8]);
    // B: direct f32 loads + cvt + swizzled LDS write
#pragma unroll
    for (int jo = 0; jo < 2; ++jo) {
#pragma unroll
      for (int jn = 0; jn < 2; ++jn) {
        const int o = wv + 4 * jo;          // k-octet 0..7
        const int nrow = nloc + 64 * jn;    // local col 0..127
        const float* p = Wc0 + 64 * jn + (size_t)(kk + o * 8) * N;
        float fv[8];
#pragma unroll
        for (int i = 0; i < 8; ++i) fv[i] = p[i * N];
        bf16x8 bv;
#pragma unroll
        for (int i = 0; i < 8; ++i) bv[i] = (__bf16)fv[i];
        *(bf16x8*)&ldsB[nrow * 64 + ((o ^ (nrow & 7)) * 8)] = bv;
      }
    }
    __syncthreads();
#pragma unroll
    for (int ks2 = 0; ks2 < 2; ++ks2) {
      const int slot8 = (sw ^ (ks2 << 2)) * 8;
      bf16x8 af[4], bf[4];
#pragma unroll
      for (int mt = 0; mt < 4; ++mt)
        af[mt] = *(const bf16x8*)&ldsA[(wr * 64 + mt * 16 + m15) * 64 + slot8];
#pragma unroll
      for (int nt = 0; nt < 4; ++nt)
        bf[nt] = *(const bf16x8*)&ldsB[(wc * 64 + nt * 16 + m15) * 64 + slot8];
#pragma unroll
      for (int mt = 0; mt < 4; ++mt)
#pragma unroll
        for (int nt = 0; nt < 4; ++nt)
          acc[mt][nt] = __builtin_amdgcn_mfma_f32_16x16x32_bf16(
              af[mt], bf[nt], acc[mt][nt], 0, 0, 0);
    }
    __syncthreads();
  }

  // epilogue: C/D layout col=lane&15, row=q*4+i
  const size_t zoff = (size_t)blockIdx.z * SLOTSP * (size_t)N;
#pragma unroll
  for (int nt = 0; nt < 4; ++nt) {
    const int c = col0 + wc * 64 + nt * 16 + m15;
    const float bv = (blockIdx.z == 0) ? bias[(size_t)e * N + c] : 0.f;
#pragma unroll
    for (int mt = 0; mt < 4; ++mt) {
      const size_t rbase = (size_t)(gr0 + wr * 64 + mt * 16 + q * 4);
      if (RELU) {
        unsigned short* Cp = (unsigned short*)Cout;
#pragma unroll
        for (int i = 0; i < 4; ++i)
          Cp[(rbase + i) * N + c] = f2bf(fmaxf(acc[mt][nt][i] + bv, 0.f));
      } else {
        float* Cp = (float*)Cout + zoff;
#pragma unroll
        for (int i = 0; i < 4; ++i)
          Cp[(rbase + i) * N + c] = acc[mt][nt][i] + bv;
      }
    }
  }
}

// sums the two split-K partial planes of y
__global__ __launch_bounds__(256) void combine_kernel(
    const float* __restrict__ y, const int* __restrict__ pair_slot,
    const float* __restrict__ out_w, float* __restrict__ out)
{
  const int gid = blockIdx.x * 256 + threadIdx.x;
  if (gid >= TOKENS * (D_MODEL / 4)) return;
  const int t = gid >> 8;
  const int qd = gid & 255;
  const float w0 = out_w[t * 2 + 0], w1 = out_w[t * 2 + 1];
  const int p0 = pair_slot[t * 2 + 0], p1 = pair_slot[t * 2 + 1];
  const float* y1 = y + (size_t)SLOTSP * D_MODEL;
  const float4 a0 = *(const float4*)(y  + (size_t)p0 * D_MODEL + qd * 4);
  const float4 a1 = *(const float4*)(y1 + (size_t)p0 * D_MODEL + qd * 4);
  const float4 b0 = *(const float4*)(y  + (size_t)p1 * D_MODEL + qd * 4);
  const float4 b1 = *(const float4*)(y1 + (size_t)p1 * D_MODEL + qd * 4);
  float4 o;
  o.x = w0 * (a0.x + a1.x) + w1 * (b0.x + b1.x);
  o.y = w0 * (a0.y + a1.y) + w1 * (b0.y + b1.y);
  o.z = w0 * (a0.z + a1.z) + w1 * (b0.z + b1.z);
  o.w = w0 * (a0.w + a1.w) + w1 * (b0.w + b1.w);
  *(float4*)(out + (size_t)t * D_MODEL + qd * 4) = o;
}

extern "C" void kernel_launch(void* const* d_in, const int* in_sizes, int n_in,
                              void* d_out, int out_size, void* d_ws, size_t ws_size,
                              hipStream_t stream)
{
  (void)in_sizes; (void)n_in; (void)out_size; (void)ws_size;
  const float* x  = (const float*)d_in[0];
  const float* gw = (const float*)d_in[1];
  const float* w1 = (const float*)d_in[2];
  const float* b1 = (const float*)d_in[3];
  const float* w2 = (const float*)d_in[4];
  const float* b2 = (const float*)d_in[5];

  float* out        = (float*)d_out;
  float* out_logits = out + (size_t)TOKENS * D_MODEL;
  float* out_idx    = out_logits + (size_t)TOKENS * NEXP;
  float* out_w      = out_idx + (size_t)TOKENS * 2;

  int* wsI       = (int*)d_ws;
  int* po        = wsI + 16;
  int* tok_list  = wsI + 512;
  int* pair_slot = wsI + 10240;
  unsigned short* xg = (unsigned short*)((char*)d_ws + (1 << 17));
  unsigned short* h  = xg + (size_t)SLOTSP * D_MODEL;            // bf16 [SLOTSP][D_FF]
  float*          y  = (float*)(h + (size_t)SLOTSP * D_FF);      // 2 x f32 [SLOTSP][D_MODEL]

  router_kernel<<<TOKENS / 4, 256, 0, stream>>>(x, gw, out_logits, out_idx, out_w);
  count_offsets_kernel<<<1, 256, 0, stream>>>(out_idx, wsI, tok_list);
  scatter_kernel<<<SLOTS / 256, 256, 0, stream>>>(out_idx, wsI + 8, po, pair_slot, tok_list);
  gather_cvt<<<SLOTSP * 128 / 256, 256, 0, stream>>>(x, tok_list, xg);
  gemm_mfma<1><<<dim3(D_FF / 128, 72, 1), 256, 0, stream>>>(
      xg, w1, b1, (void*)h, wsI, D_MODEL, D_FF);
  gemm_mfma<0><<<dim3(D_MODEL / 128, 72, 2), 256, 0, stream>>>(
      h, w2, b2, (void*)y, wsI, D_FF, D_MODEL);
  combine_kernel<<<(TOKENS * D_MODEL / 4) / 256, 256, 0, stream>>>(
      y, pair_slot, out_w, out);
}

// Round 5
// 595.668 us; speedup vs baseline: 1.0007x; 1.0007x over previous
//
#include <hip/hip_runtime.h>
#include <cstdint>
#include <cstddef>

// MoE layer, MI355X. Round 8: panel-major XCD chunk ordering for the fused
// B-cvt GEMM. Round-7 measurement: fused f32 B staging tripled FETCH
// (113->400MB) because f32 weights broke L3-fit and the row-major chunk
// order had panel-reuse distance 32 (spilled L2 too). Fix: within each XCD
// chunk, iterate panel-major (bx = j/R, by = xcd*R + j%R, R = cpx/gx = 9):
// the 9 row-blocks sharing one 512KB/1MB weight panel run adjacent on one
// XCD -> panel fetched once, served 9x from that XCD's 4MB L2.
// Everything else unchanged: single-buffer 32KB LDS (5 blocks/CU), fused
// direct-f32 B staging (no transpose kernels), split-K x2 GEMM2, 7 launches.
// T=4096, D=1024, F=4096, E=8, top-2. Padded slots: 9216.

#define D_MODEL 1024
#define D_FF    4096
#define NEXP    8
#define TOKENS  4096
#define SLOTS   8192
#define SLOTSP  9216

typedef __bf16 bf16x8 __attribute__((ext_vector_type(8)));
typedef float  f32x4  __attribute__((ext_vector_type(4)));

static __device__ __forceinline__ unsigned short f2bf(float f) {
  unsigned int u = __float_as_uint(f);
  u += 0x7fffu + ((u >> 16) & 1u);   // RNE
  return (unsigned short)(u >> 16);
}

static __device__ __forceinline__ void async_ld16(const void* g, void* l) {
  __builtin_amdgcn_global_load_lds(
      (const __attribute__((address_space(1))) void*)g,
      (__attribute__((address_space(3))) void*)l, 16, 0, 0);
}

// ---------------- setup kernels ----------------

// one wave per token; no atomics
__global__ __launch_bounds__(256) void router_kernel(
    const float* __restrict__ x, const float* __restrict__ gw,
    float* __restrict__ out_logits, float* __restrict__ out_idx,
    float* __restrict__ out_w)
{
  const int w = threadIdx.x >> 6, lane = threadIdx.x & 63;
  const int t = blockIdx.x * 4 + w;
  float p[NEXP];
#pragma unroll
  for (int e = 0; e < NEXP; ++e) p[e] = 0.f;
  const float* xr = x + (size_t)t * D_MODEL;
#pragma unroll 4
  for (int i = 0; i < D_MODEL / 64; ++i) {
    const int d = i * 64 + lane;
    const float xv = xr[d];
    const float* g = gw + (size_t)d * NEXP;
#pragma unroll
    for (int e = 0; e < NEXP; ++e) p[e] += xv * g[e];
  }
#pragma unroll
  for (int e = 0; e < NEXP; ++e) {
#pragma unroll
    for (int s = 1; s < 64; s <<= 1) p[e] += __shfl_xor(p[e], s, 64);
  }
  if (lane == 0) {
    int i0 = 0;
#pragma unroll
    for (int e = 1; e < NEXP; ++e) if (p[e] > p[i0]) i0 = e;
    int i1 = (i0 == 0) ? 1 : 0;
#pragma unroll
    for (int e = 0; e < NEXP; ++e)
      if (e != i0 && p[e] > p[i1]) i1 = e;
    const float w0 = 1.f / (1.f + __expf(p[i1] - p[i0]));
#pragma unroll
    for (int e = 0; e < NEXP; ++e) out_logits[(size_t)t * NEXP + e] = p[e];
    out_idx[t * 2 + 0] = (float)i0;
    out_idx[t * 2 + 1] = (float)i1;
    out_w[t * 2 + 0] = w0;
    out_w[t * 2 + 1] = 1.f - w0;
  }
}

// single block: tok_list init + histogram + padded offsets + block map + cursors
// wsI: [8..16)=cursor [16..25)=po [25]=nb [32..104)=blk_e [128..200)=blk_gr0
__global__ __launch_bounds__(256) void count_offsets_kernel(
    const float* __restrict__ out_idx, int* __restrict__ wsI,
    int* __restrict__ tok_list)
{
  __shared__ int hist[NEXP];
  const int tid = threadIdx.x;
  for (int i = tid; i < SLOTSP; i += 256) tok_list[i] = -1;
  if (tid < NEXP) hist[tid] = 0;
  if (tid < NEXP) wsI[8 + tid] = 0;   // cursors
  __syncthreads();
  int c[NEXP];
#pragma unroll
  for (int e = 0; e < NEXP; ++e) c[e] = 0;
  for (int p = tid; p < SLOTS; p += 256) c[(int)out_idx[p]]++;  // coalesced
#pragma unroll
  for (int e = 0; e < NEXP; ++e) if (c[e]) atomicAdd(&hist[e], c[e]);
  __syncthreads();
  if (tid == 0) {
    int s = 0, nb = 0;
    for (int e = 0; e < NEXP; ++e) {
      wsI[16 + e] = s;
      const int nblk = (hist[e] + 127) >> 7;
      for (int j = 0; j < nblk; ++j) {
        wsI[32 + nb] = e;
        wsI[128 + nb] = s + j * 128;
        ++nb;
      }
      s += nblk << 7;
    }
    wsI[16 + NEXP] = s;
    wsI[25] = nb;
  }
}

// ballot-aggregated per-wave atomics (~8 per wave instead of 64)
__global__ void scatter_kernel(const float* __restrict__ out_idx,
                               int* __restrict__ cursor,
                               const int* __restrict__ po,
                               int* __restrict__ pair_slot,
                               int* __restrict__ tok_list)
{
  const int p = blockIdx.x * 256 + threadIdx.x;
  const int lane = threadIdx.x & 63;
  const int e = (int)out_idx[p];
  int pos = 0;
#pragma unroll
  for (int e8 = 0; e8 < NEXP; ++e8) {
    const unsigned long long m = __ballot(e == e8);
    if (m) {
      const int leader = __ffsll((long long)m) - 1;
      int base = 0;
      if (lane == leader) base = atomicAdd(&cursor[e8], (int)__popcll(m));
      base = __shfl(base, leader, 64);
      if (e == e8)
        pos = po[e8] + base +
              (int)__popcll(m & ((1ull << lane) - 1ull));
    }
  }
  tok_list[pos] = p >> 1;
  pair_slot[p] = pos;
}

// gather x rows into slot order, f32 -> bf16
__global__ __launch_bounds__(256) void gather_cvt(
    const float* __restrict__ x, const int* __restrict__ tok_list,
    unsigned short* __restrict__ xg)
{
  const int gid = blockIdx.x * 256 + threadIdx.x;
  const int row = gid >> 7, seg = gid & 127;
  const int tok = tok_list[row];
  if (tok < 0) return;
  const float* src = x + (size_t)tok * D_MODEL + seg * 8;
  const float4 a = *(const float4*)(src);
  const float4 b = *(const float4*)(src + 4);
  ushort4 lo = make_ushort4(f2bf(a.x), f2bf(a.y), f2bf(a.z), f2bf(a.w));
  ushort4 hi = make_ushort4(f2bf(b.x), f2bf(b.y), f2bf(b.z), f2bf(b.w));
  unsigned short* d = xg + (size_t)row * D_MODEL + seg * 8;
  *(ushort4*)(d) = lo;
  *(ushort4*)(d + 4) = hi;
}

// ------- MFMA grouped GEMM, BK=64, single-buffer, split-K, fused B-cvt -------
// ldsA: 128 rows x 8 segs(16B); data seg s of row r at slot s^(r&7); staged via
//   global_load_lds with pre-swizzled per-lane global source.
// ldsB: same layout, staged directly from f32 [K][N] weights: thread
//   (wave wv, lane nloc) handles columns n=nloc+64*jn, k-octets o=wv+4*jo;
//   8 k-strided dword loads (wave-coalesced 256B), RNE __bf16 cvt, one
//   swizzled ds_write_b128 at slot o^(n&7).
// Fragment read: seg = ks2*4+q -> slot = (q ^ (m15&7)) ^ (ks2*4).
// Block mapping: xcd = orig&7 owns chunk of cpx blocks; within the chunk,
//   PANEL-MAJOR: bx = j/R, by = xcd*R + j%R (R = cpx/gx = 9 for both GEMMs).
//   The R row-blocks sharing one weight col-panel are adjacent on one XCD ->
//   panel fetched from HBM once, reused R x from that XCD's L2.
// 32KB LDS -> 5 blocks/CU co-resident. Split-K via blockIdx.z (partials f32,
// bias added by split 0 only; RELU instance never split).
template <int RELU>
__global__ __launch_bounds__(256) void gemm_mfma(
    const unsigned short* __restrict__ A, const float* __restrict__ W,
    const float* __restrict__ bias, void* __restrict__ Cout,
    const int* __restrict__ wsI, int K, int N)
{
  const int gx = gridDim.x;
  const int nwg = gx * gridDim.y;
  const int cpx = nwg >> 3;          // blocks per XCD chunk
  const int R = cpx / gx;            // row-blocks per chunk (exact: 9)
  const int orig = blockIdx.y * gx + blockIdx.x;
  const int xcd = orig & 7;
  const int j = orig >> 3;           // position within chunk
  const int bx = j / R;
  const int by = xcd * R + (j - bx * R);

  if (by >= wsI[25]) return;
  const int e   = wsI[32 + by];
  const int gr0 = wsI[128 + by];
  const int col0 = bx * 128;

  const int klen = K / gridDim.z;
  const int kbeg = blockIdx.z * klen;
  const int kend = kbeg + klen;

  __shared__ unsigned short ldsA[128 * 64];
  __shared__ unsigned short ldsB[128 * 64];

  const int tid = threadIdx.x;
  const int lane = tid & 63;
  const int w = tid >> 6;
  const int wr = w >> 1, wc = w & 1;
  const int m15 = lane & 15, q = lane >> 4;

  f32x4 zero = {0.f, 0.f, 0.f, 0.f};
  f32x4 acc[4][4];
#pragma unroll
  for (int mt = 0; mt < 4; ++mt)
#pragma unroll
    for (int nt = 0; nt < 4; ++nt) acc[mt][nt] = zero;

  // A staging offsets (halfs): row0 = tid>>3, sg = (tid&7)^((tid>>3)&7)
  const size_t off0 = (size_t)(tid >> 3) * K + ((tid & 7) ^ ((tid >> 3) & 7)) * 8;
  const size_t jstep = (size_t)32 * K;
  const unsigned short* Abase = A + (size_t)gr0 * K;

  // B staging: column base for this thread (f32 weights, row stride N)
  const int nloc = tid & 63;
  const int wv = tid >> 6;
  const float* Wc0 = W + (size_t)e * K * N + (col0 + nloc);

  const int sw = q ^ (m15 & 7);   // fragment slot base

  for (int kk = kbeg; kk < kend; kk += 64) {
    // A: async global->LDS (bf16 source)
#pragma unroll
    for (int j4 = 0; j4 < 4; ++j4)
      async_ld16(Abase + off0 + j4 * jstep + kk, &ldsA[(j4 * 256 + tid) * 8]);
    // B: direct f32 loads + cvt + swizzled LDS write
#pragma unroll
    for (int jo = 0; jo < 2; ++jo) {
#pragma unroll
      for (int jn = 0; jn < 2; ++jn) {
        const int o = wv + 4 * jo;          // k-octet 0..7
        const int nrow = nloc + 64 * jn;    // local col 0..127
        const float* p = Wc0 + 64 * jn + (size_t)(kk + o * 8) * N;
        float fv[8];
#pragma unroll
        for (int i = 0; i < 8; ++i) fv[i] = p[i * N];
        bf16x8 bv;
#pragma unroll
        for (int i = 0; i < 8; ++i) bv[i] = (__bf16)fv[i];
        *(bf16x8*)&ldsB[nrow * 64 + ((o ^ (nrow & 7)) * 8)] = bv;
      }
    }
    __syncthreads();
#pragma unroll
    for (int ks2 = 0; ks2 < 2; ++ks2) {
      const int slot8 = (sw ^ (ks2 << 2)) * 8;
      bf16x8 af[4], bf[4];
#pragma unroll
      for (int mt = 0; mt < 4; ++mt)
        af[mt] = *(const bf16x8*)&ldsA[(wr * 64 + mt * 16 + m15) * 64 + slot8];
#pragma unroll
      for (int nt = 0; nt < 4; ++nt)
        bf[nt] = *(const bf16x8*)&ldsB[(wc * 64 + nt * 16 + m15) * 64 + slot8];
#pragma unroll
      for (int mt = 0; mt < 4; ++mt)
#pragma unroll
        for (int nt = 0; nt < 4; ++nt)
          acc[mt][nt] = __builtin_amdgcn_mfma_f32_16x16x32_bf16(
              af[mt], bf[nt], acc[mt][nt], 0, 0, 0);
    }
    __syncthreads();
  }

  // epilogue: C/D layout col=lane&15, row=q*4+i
  const size_t zoff = (size_t)blockIdx.z * SLOTSP * (size_t)N;
#pragma unroll
  for (int nt = 0; nt < 4; ++nt) {
    const int c = col0 + wc * 64 + nt * 16 + m15;
    const float bv = (blockIdx.z == 0) ? bias[(size_t)e * N + c] : 0.f;
#pragma unroll
    for (int mt = 0; mt < 4; ++mt) {
      const size_t rbase = (size_t)(gr0 + wr * 64 + mt * 16 + q * 4);
      if (RELU) {
        unsigned short* Cp = (unsigned short*)Cout;
#pragma unroll
        for (int i = 0; i < 4; ++i)
          Cp[(rbase + i) * N + c] = f2bf(fmaxf(acc[mt][nt][i] + bv, 0.f));
      } else {
        float* Cp = (float*)Cout + zoff;
#pragma unroll
        for (int i = 0; i < 4; ++i)
          Cp[(rbase + i) * N + c] = acc[mt][nt][i] + bv;
      }
    }
  }
}

// sums the two split-K partial planes of y
__global__ __launch_bounds__(256) void combine_kernel(
    const float* __restrict__ y, const int* __restrict__ pair_slot,
    const float* __restrict__ out_w, float* __restrict__ out)
{
  const int gid = blockIdx.x * 256 + threadIdx.x;
  if (gid >= TOKENS * (D_MODEL / 4)) return;
  const int t = gid >> 8;
  const int qd = gid & 255;
  const float w0 = out_w[t * 2 + 0], w1 = out_w[t * 2 + 1];
  const int p0 = pair_slot[t * 2 + 0], p1 = pair_slot[t * 2 + 1];
  const float* y1 = y + (size_t)SLOTSP * D_MODEL;
  const float4 a0 = *(const float4*)(y  + (size_t)p0 * D_MODEL + qd * 4);
  const float4 a1 = *(const float4*)(y1 + (size_t)p0 * D_MODEL + qd * 4);
  const float4 b0 = *(const float4*)(y  + (size_t)p1 * D_MODEL + qd * 4);
  const float4 b1 = *(const float4*)(y1 + (size_t)p1 * D_MODEL + qd * 4);
  float4 o;
  o.x = w0 * (a0.x + a1.x) + w1 * (b0.x + b1.x);
  o.y = w0 * (a0.y + a1.y) + w1 * (b0.y + b1.y);
  o.z = w0 * (a0.z + a1.z) + w1 * (b0.z + b1.z);
  o.w = w0 * (a0.w + a1.w) + w1 * (b0.w + b1.w);
  *(float4*)(out + (size_t)t * D_MODEL + qd * 4) = o;
}

extern "C" void kernel_launch(void* const* d_in, const int* in_sizes, int n_in,
                              void* d_out, int out_size, void* d_ws, size_t ws_size,
                              hipStream_t stream)
{
  (void)in_sizes; (void)n_in; (void)out_size; (void)ws_size;
  const float* x  = (const float*)d_in[0];
  const float* gw = (const float*)d_in[1];
  const float* w1 = (const float*)d_in[2];
  const float* b1 = (const float*)d_in[3];
  const float* w2 = (const float*)d_in[4];
  const float* b2 = (const float*)d_in[5];

  float* out        = (float*)d_out;
  float* out_logits = out + (size_t)TOKENS * D_MODEL;
  float* out_idx    = out_logits + (size_t)TOKENS * NEXP;
  float* out_w      = out_idx + (size_t)TOKENS * 2;

  int* wsI       = (int*)d_ws;
  int* po        = wsI + 16;
  int* tok_list  = wsI + 512;
  int* pair_slot = wsI + 10240;
  unsigned short* xg = (unsigned short*)((char*)d_ws + (1 << 17));
  unsigned short* h  = xg + (size_t)SLOTSP * D_MODEL;            // bf16 [SLOTSP][D_FF]
  float*          y  = (float*)(h + (size_t)SLOTSP * D_FF);      // 2 x f32 [SLOTSP][D_MODEL]

  router_kernel<<<TOKENS / 4, 256, 0, stream>>>(x, gw, out_logits, out_idx, out_w);
  count_offsets_kernel<<<1, 256, 0, stream>>>(out_idx, wsI, tok_list);
  scatter_kernel<<<SLOTS / 256, 256, 0, stream>>>(out_idx, wsI + 8, po, pair_slot, tok_list);
  gather_cvt<<<SLOTSP * 128 / 256, 256, 0, stream>>>(x, tok_list, xg);
  gemm_mfma<1><<<dim3(D_FF / 128, 72, 1), 256, 0, stream>>>(
      xg, w1, b1, (void*)h, wsI, D_MODEL, D_FF);
  gemm_mfma<0><<<dim3(D_MODEL / 128, 72, 2), 256, 0, stream>>>(
      h, w2, b2, (void*)y, wsI, D_FF, D_MODEL);
  combine_kernel<<<(TOKENS * D_MODEL / 4) / 256, 256, 0, stream>>>(
      y, pair_slot, out_w, out);
}